// Round 9
// baseline (189.893 us; speedup 1.0000x reference)
//
#include <hip/hip_runtime.h>

// SGE-style gate: B=64, C=512, HW=784, G=8, cpg=64. One block per (b,g).
//
// R12: wave-autonomous pipeline. R9/R11 post-mortem: traffic clean (154MB)
// but ~38us of the 62-64us is lockstep stall -- 3 block-wide barriers x
// 16-24 chunk iterations/CU, all waves stalling at the same point (1
// block/CU). R11 proved more waves / store interleave don't help while the
// barrier cadence remains. Fix: vmcnt is PER-WAVE -> each wave owns 8
// channel-rows, runs a private double-buffered row pipeline (DMA own row,
// counted own-vmcnt wait, ds_read row once to regs, mean via intra-wave
// shuffles, accumulate mean_r*x[r,p] in REGISTERS (13 floats/lane), park
// fp16). ZERO barriers during staging+reduce; waves drift and cover each
// other's waits. Then just 4 barriers: combine 8 partial-s (reusing freed
// stage), mu/var, gate, epilogue from park.
// Traffic stays 1 read + 1 write (FETCH~50MB w/ LLC help, WRITE~100MB).
//
// LDS: park fp16 100352 + stage 16x3136=50176 + gate 3136 + red 64
//    = 153728 B (dynamic; 1 block/CU).

#define HW      784
#define HW4     196
#define NG      8
#define TILE_F  50176
#define NCH     8            // rows per wave

typedef float    f32x4 __attribute__((ext_vector_type(4)));
typedef _Float16 f16x4 __attribute__((ext_vector_type(4)));

#define XH_OFF    0
#define ST_OFF    100352
#define GB_OFF    150528
#define RED_OFF   153664
#define LDS_TOTAL 153728

__device__ __forceinline__ void gload16(const float* g, float* l) {
    __builtin_amdgcn_global_load_lds(
        (const __attribute__((address_space(1))) void*)g,
        (__attribute__((address_space(3))) void*)l, 16, 0, 0);
}

#define WAIT_LGKM() asm volatile("s_waitcnt lgkmcnt(0)" ::: "memory")
#define RAW_BAR()   do { __builtin_amdgcn_s_barrier(); \
                         __builtin_amdgcn_sched_barrier(0); } while (0)

__global__ __launch_bounds__(512, 1)
void sge_kernel(const float* __restrict__ x, const float* __restrict__ weight,
                const float* __restrict__ bias, float* __restrict__ out) {
    extern __shared__ char smem[];
    _Float16* xh   = (_Float16*)(smem + XH_OFF);   // fp16 park [64][784]
    float*    stg  = (float*)(smem + ST_OFF);      // 16 row-slots (2/wave)
    float*    gbuf = (float*)(smem + GB_OFF);      // gate[784]
    float*    red  = (float*)(smem + RED_OFF);     // 16 reduce slots

    const int t = threadIdx.x, lane = t & 63, wave = t >> 6;   // 8 waves
    const int bg = blockIdx.x, g = bg & (NG - 1);
    const float* xt = x + (size_t)bg * TILE_F;

    float wg = weight[g], bv = bias[g];
    asm volatile("" : "+v"(wg), "+v"(bv));   // materialize before DMA issue

    const int wrow = wave * NCH;             // this wave's first channel-row
    float* slot0 = stg + (wave * 2) * HW;    // wave-private double buffer
    float* slot1 = stg + (wave * 2 + 1) * HW;

    // DMA one row (3136B = 3x1KB + 64B tail) into the wave's slot.
    // 4 VMEM instrs/row for EVERY wave (tail exec-masked, still counts 1).
    auto issue_row = [&](int r) {
        const float* gs = xt + (size_t)(wrow + r) * HW;
        float* ld = (r & 1) ? slot1 : slot0;
        gload16(gs + lane * 4,       ld);
        gload16(gs + 256 + lane * 4, ld + 256);
        gload16(gs + 512 + lane * 4, ld + 512);
        if (lane < 4) gload16(gs + 768 + lane * 4, ld + 768);
    };

    issue_row(0);
    issue_row(1);

    f32x4 acc0 = {0.f,0.f,0.f,0.f}, acc1 = {0.f,0.f,0.f,0.f};
    f32x4 acc2 = {0.f,0.f,0.f,0.f}, acc3 = {0.f,0.f,0.f,0.f};

    // ---- wave-private row loop: NO BARRIERS ----
#pragma unroll
    for (int r = 0; r < NCH; ++r) {
        if (r < NCH - 1) asm volatile("s_waitcnt vmcnt(4)" ::: "memory");
        else             asm volatile("s_waitcnt vmcnt(0)" ::: "memory");
        __builtin_amdgcn_sched_barrier(0);

        const f32x4* s4 = (const f32x4*)((r & 1) ? slot1 : slot0);
        const f32x4 v0 = s4[lane], v1 = s4[lane + 64], v2 = s4[lane + 128];
        f32x4 v3 = {0.f,0.f,0.f,0.f};
        if (lane < 4) v3 = s4[192 + lane];

        float m = ((v0.x + v0.y) + (v0.z + v0.w))
                + ((v1.x + v1.y) + (v1.z + v1.w))
                + ((v2.x + v2.y) + (v2.z + v2.w))
                + ((v3.x + v3.y) + (v3.z + v3.w));
#pragma unroll
        for (int d = 1; d < 64; d <<= 1) m += __shfl_xor(m, d, 64);
        m *= (1.0f / (float)HW);

        acc0 += m * v0; acc1 += m * v1; acc2 += m * v2; acc3 += m * v3;

        f16x4* ph = (f16x4*)xh + (wrow + r) * HW4;
        ph[lane]       = __builtin_convertvector(v0, f16x4);
        ph[lane + 64]  = __builtin_convertvector(v1, f16x4);
        ph[lane + 128] = __builtin_convertvector(v2, f16x4);
        if (lane < 4) ph[192 + lane] = __builtin_convertvector(v3, f16x4);

        __builtin_amdgcn_sched_barrier(0);
        if (r + 2 < NCH) issue_row(r + 2);   // refill the slot just consumed
    }

    // ---- barrier 1: combine 8 per-wave partial-s vectors via freed stage ----
    WAIT_LGKM(); RAW_BAR();
    {
        f32x4* cw = (f32x4*)(stg + wave * HW);
        cw[lane] = acc0; cw[lane + 64] = acc1; cw[lane + 128] = acc2;
        if (lane < 4) cw[192 + lane] = acc3;
    }
    WAIT_LGKM(); RAW_BAR();                  // barrier 2

    const bool has1 = t < (HW - 512);        // t < 272
    float s0 = 0.f, s1 = 0.f;
#pragma unroll
    for (int w = 0; w < 8; ++w) {
        s0 += stg[w * HW + t];
        if (has1) s1 += stg[w * HW + t + 512];
    }

    float rs  = s0 + (has1 ? s1 : 0.f);
    float rs2 = s0 * s0 + (has1 ? s1 * s1 : 0.f);
#pragma unroll
    for (int d = 1; d < 64; d <<= 1) {
        rs  += __shfl_xor(rs,  d, 64);
        rs2 += __shfl_xor(rs2, d, 64);
    }
    if (lane == 0) { red[wave] = rs; red[8 + wave] = rs2; }
    WAIT_LGKM(); RAW_BAR();                  // barrier 3

    float ss = 0.f, ss2 = 0.f;
#pragma unroll
    for (int w = 0; w < 8; ++w) { ss += red[w]; ss2 += red[8 + w]; }
    const float mu   = ss * (1.0f / (float)HW);
    const float var  = ss2 * (1.0f / (float)HW) - mu * mu;
    const float rstd = rsqrtf(var + 1e-5f);

    gbuf[t] = 1.0f / (1.0f + __expf(-((s0 - mu) * rstd * wg + bv)));
    if (has1)
        gbuf[t + 512] = 1.0f / (1.0f + __expf(-((s1 - mu) * rstd * wg + bv)));
    WAIT_LGKM(); RAW_BAR();                  // barrier 4

    // ---- epilogue: out = f32(park) * gate, plain coalesced stores ----
    const f32x4* gb4 = (const f32x4*)gbuf;
    const f16x4* px  = (const f16x4*)xh;
    f32x4* o4 = (f32x4*)(out + (size_t)bg * TILE_F);
    int col = t % HW4;
#pragma unroll
    for (int rr = 0; rr < 24; ++rr) {
        const int idx = t + rr * 512;
        o4[idx] = __builtin_convertvector(px[idx], f32x4) * gb4[col];
        col += 120; if (col >= HW4) col -= HW4;   // 512 mod 196
    }
    if (t < 256) {
        const int idx = 12288 + t;
        o4[idx] = __builtin_convertvector(px[idx], f32x4) * gb4[idx % HW4];
    }
}

extern "C" void kernel_launch(void* const* d_in, const int* in_sizes, int n_in,
                              void* d_out, int out_size, void* d_ws, size_t ws_size,
                              hipStream_t stream) {
    const float* x      = (const float*)d_in[0];
    const float* weight = (const float*)d_in[1];
    const float* bias   = (const float*)d_in[2];
    float* out = (float*)d_out;

    static bool init = false;
    if (!init) {
        (void)hipFuncSetAttribute((const void*)sge_kernel,
                                  hipFuncAttributeMaxDynamicSharedMemorySize,
                                  LDS_TOTAL);
        init = true;
    }
    sge_kernel<<<dim3(512), dim3(512), LDS_TOTAL, stream>>>(x, weight, bias, out);
}